// Round 21
// baseline (35.024 us; speedup 1.0000x reference)
//
#include <hip/hip_runtime.h>
#include <math.h>

#define CC 30
#define NBATCH 4096
#define NIJ 49
#define NPAIR 1225            // 49 ij * 25 tail channels (c = 5..29) = 25 * 49
#define PSTR 7352             // per-wg partial stride in floats (6*NPAIR=7350, padded to /4)
#define THREADS 512
#define SLABF4 1470           // float4 count of a 4-batch slab of one tensor
#define SLABF  5880           // floats per 4-batch slab

// ws layout (NO initialization required — every read location is written first):
//   offset 0      : scal[nwg][4]     (written by yolo_main)
//   offset 4096   : cont[25]         (written by yolo_reduce)
//   offset 8192   : parts[nwg][PSTR] (written by yolo_main)

__global__ __launch_bounds__(THREADS)
void yolo_main(const float* __restrict__ y, const float* __restrict__ yh,
               float* __restrict__ scal, float* __restrict__ parts, int nwg)
{
    __shared__ __align__(16) float tY[2][SLABF];   // 2 x 23.5 KB
    __shared__ __align__(16) float tH[2][SLABF];   // 2 x 23.5 KB
    __shared__ float scr[4][8];

    const int tid = threadIdx.x;
    const int wg  = blockIdx.x;
    const int bpw = NBATCH / nwg;        // 16 for nwg=256
    const int nslab = bpw >> 2;          // 4

    const int i0 = tid, i1 = tid + 512;
    const int i2r = tid + 1024;
    const int i2  = (i2r < SLABF4) ? i2r : (SLABF4 - 1);
    const bool w2 = (i2r < SLABF4);

    int  ijv[3], cv[3], pr[3];
    bool val[3];
    #pragma unroll
    for (int i = 0; i < 3; i++) {
        int p = tid + i * THREADS;
        val[i] = (p < NPAIR);
        pr[i]  = p;
        int pp = val[i] ? p : 0;
        ijv[i] = pp / 25;
        cv[i]  = 5 + pp % 25;
    }

    float D0[3] = {0,0,0}, B0[3] = {0,0,0}, C0[3] = {0,0,0};
    float D1[3] = {0,0,0}, B1[3] = {0,0,0}, C1[3] = {0,0,0};
    float obj = 0.f, noobj = 0.f, coord = 0.f, tt = 0.f;

    const float4* Yg = (const float4*)y;
    const float4* Hg = (const float4*)yh;

    // prologue: stage slab 0 into buffer 0
    {
        const size_t f4 = (size_t)((wg * bpw) >> 2) * SLABF4;
        float4 a0 = Yg[f4+i0], a1 = Yg[f4+i1], a2 = Yg[f4+i2];
        float4 b0 = Hg[f4+i0], b1 = Hg[f4+i1], b2 = Hg[f4+i2];
        float4* dY = (float4*)tY[0];
        float4* dH = (float4*)tH[0];
        dY[i0] = a0; dY[i1] = a1; if (w2) dY[i2] = a2;
        dH[i0] = b0; dH[i1] = b1; if (w2) dH[i2] = b2;
    }
    __syncthreads();

    for (int s = 0; s < nslab; s++) {
        const float* cy = tY[s & 1];
        const float* ch = tH[s & 1];
        const bool pf = (s + 1 < nslab);
        float4 ry0, ry1, ry2, rh0, rh1, rh2;
        if (pf) {                 // issue next slab's loads; they fly during compute
            const size_t nf4 = (size_t)((wg * bpw + (s+1)*4) >> 2) * SLABF4;
            ry0 = Yg[nf4+i0]; ry1 = Yg[nf4+i1]; ry2 = Yg[nf4+i2];
            rh0 = Hg[nf4+i0]; rh1 = Hg[nf4+i1]; rh2 = Hg[nf4+i2];
        }

        // ---- pointwise: 196 cells in this slab ----
        if (tid < 4 * NIJ) {
            const int base = tid * CC;
            float y0 = cy[base],     h0 = ch[base];
            float y5 = cy[base + 5], h5 = ch[base + 5];
            float d0 = y0 - h0; d0 *= d0;
            float d5 = y5 - h5; d5 *= d5;
            const bool m0 = (y0 == 1.0f), m1 = (y5 == 1.0f);
            obj   += (m0 ? d0 : 0.f) + (m1 ? d5 : 0.f);
            noobj += (m0 ? 0.f : d0) + (m1 ? 0.f : d5);
            if (m0) {
                float a  = cy[base + 1] - ch[base + 1];
                float b2 = cy[base + 2] - ch[base + 2];
                float c1 = sqrtf(cy[base + 3]) - sqrtf(ch[base + 3]);
                float c2 = sqrtf(cy[base + 4]) - sqrtf(ch[base + 4]);
                coord += a * a + b2 * b2 + c1 * c1 + c2 * c2;
            }
            if (m1) {
                float a  = cy[base + 6] - ch[base + 6];
                float b2 = cy[base + 7] - ch[base + 7];
                float c1 = sqrtf(cy[base + 8]) - sqrtf(ch[base + 8]);
                float c2 = sqrtf(cy[base + 9]) - sqrtf(ch[base + 9]);
                coord += a * a + b2 * b2 + c1 * c1 + c2 * c2;
            }
        }

        // ---- slot phase: register accumulation, no atomics ----
        #pragma unroll
        for (int b = 0; b < 4; b++) {
            #pragma unroll
            for (int i = 0; i < 3; i++) {
                if (!val[i]) continue;
                const int cb = b * 1470 + ijv[i] * CC;
                const float w0 = (cy[cb] == 1.0f) ? 1.f : 0.f;
                const float wk = (cv[i] >= 10 && cy[cb + 5] == 1.0f) ? 1.f : 0.f;
                const float t  = cy[cb + cv[i]];
                const float th = ch[cb + cv[i]];
                const float e  = __expf(th);
                const float te = t * e, ee = e * e, t2 = t * t;
                D0[i] = fmaf(e,  w0, D0[i]);
                B0[i] = fmaf(te, w0, B0[i]);
                C0[i] = fmaf(ee, w0, C0[i]);
                D1[i] = fmaf(e,  wk, D1[i]);
                B1[i] = fmaf(te, wk, B1[i]);
                C1[i] = fmaf(ee, wk, C1[i]);
                tt = fmaf(t2, w0 + wk, tt);
            }
        }

        // ---- write prefetched slab into the other buffer; ONE barrier per slab ----
        if (pf) {
            float4* dY = (float4*)tY[(s + 1) & 1];
            float4* dH = (float4*)tH[(s + 1) & 1];
            dY[i0] = ry0; dY[i1] = ry1; if (w2) dY[i2] = ry2;
            dH[i0] = rh0; dH[i1] = rh1; if (w2) dH[i2] = rh2;
        }
        __syncthreads();
    }

    // ---- per-wg partials: contiguous block, coalesced stores ----
    float* pp = parts + (size_t)wg * PSTR;
    #pragma unroll
    for (int i = 0; i < 3; i++) {
        if (!val[i]) continue;
        const int p = pr[i];
        pp[p]            = D0[i];
        pp[NPAIR + p]    = B0[i];
        pp[2*NPAIR + p]  = C0[i];
        pp[3*NPAIR + p]  = D1[i];   // zero when cv<10
        pp[4*NPAIR + p]  = B1[i];
        pp[5*NPAIR + p]  = C1[i];
    }

    // ---- scalar sums: shuffle -> LDS -> 4 floats per wg ----
    const int lane = tid & 63, wv = tid >> 6;
    #pragma unroll
    for (int off = 32; off > 0; off >>= 1) {
        obj   += __shfl_down(obj,   off);
        noobj += __shfl_down(noobj, off);
        coord += __shfl_down(coord, off);
        tt    += __shfl_down(tt,    off);
    }
    if (lane == 0) { scr[0][wv] = obj; scr[1][wv] = noobj; scr[2][wv] = coord; scr[3][wv] = tt; }
    __syncthreads();
    if (tid < 4) {
        float sacc = 0.f;
        #pragma unroll
        for (int w = 0; w < THREADS / 64; w++) sacc += scr[tid][w];
        scal[wg * 4 + tid] = sacc;
    }
}

// 25 blocks x 512: block bx owns slots [49*bx, 49*bx+49). Each 64-lane sub-group
// folds nwg/8 wgs (contiguous 49-float runs per category, coalesced); LDS fold
// over the 8 subs; 49 threads compute the per-slot softmax contribution; one
// float written per block. Single stage, fixed order, no atomics.
__global__ __launch_bounds__(512)
void yolo_reduce(const float* __restrict__ parts, float* __restrict__ cont, int nwg)
{
    const int tid  = threadIdx.x;
    const int lane = tid & 63;
    const int sub  = tid >> 6;              // 0..7
    const int s0   = blockIdx.x * 49;       // slot group base
    const int wps  = nwg >> 3;              // wgs per sub-group (32 for nwg=256)

    float D0=0,B0=0,C0=0,D1=0,B1=0,C1=0;
    if (lane < 49) {
        const float* q = parts + (size_t)(sub * wps) * PSTR + s0 + lane;
        for (int w = 0; w < wps; ++w) {
            D0 += q[0];
            B0 += q[NPAIR];
            C0 += q[2*NPAIR];
            D1 += q[3*NPAIR];
            B1 += q[4*NPAIR];
            C1 += q[5*NPAIR];
            q += PSTR;
        }
    }
    __shared__ float sred[8][6][50];
    if (lane < 49) {
        sred[sub][0][lane] = D0; sred[sub][1][lane] = B0; sred[sub][2][lane] = C0;
        sred[sub][3][lane] = D1; sred[sub][4][lane] = B1; sred[sub][5][lane] = C1;
    }
    __syncthreads();

    float v = 0.f;
    if (tid < 49) {
        float d0=0,b0=0,c0=0,d1=0,b1=0,c1=0;
        #pragma unroll
        for (int k = 0; k < 8; k++) {
            d0 += sred[k][0][tid]; b0 += sred[k][1][tid]; c0 += sred[k][2][tid];
            d1 += sred[k][3][tid]; b1 += sred[k][4][tid]; c1 += sred[k][5][tid];
        }
        const int cidx = (s0 + tid) % 25;
        if (d0 > 0.f) v += c0 / (d0 * d0) - 2.f * b0 / d0;
        if (cidx >= 5 && d1 > 0.f) v += c1 / (d1 * d1) - 2.f * b1 / d1;
    }
    if (tid < 64) {
        #pragma unroll
        for (int off = 32; off > 0; off >>= 1) v += __shfl_down(v, off);
        if (tid == 0) cont[blockIdx.x] = v;
    }
}

// 1 block x 256: fold cont[25] + scal[nwg][4] -> out. ~1 KB of reads.
__global__ __launch_bounds__(256)
void yolo_final(const float* __restrict__ cont, const float* __restrict__ scal,
                float* __restrict__ out, int nwg)
{
    const int tid = threadIdx.x;
    float v = (tid < 25) ? cont[tid] : 0.f;
    const float4* s4 = (const float4*)scal;
    for (int w = tid; w < nwg; w += 256) {
        float4 a = s4[w];
        v += a.x + 0.5f * a.y + 5.0f * a.z + a.w;
    }
    __shared__ float sr[4];
    #pragma unroll
    for (int off = 32; off > 0; off >>= 1) v += __shfl_down(v, off);
    if ((tid & 63) == 0) sr[tid >> 6] = v;
    __syncthreads();
    if (tid == 0) out[0] = (sr[0] + sr[1] + sr[2] + sr[3]) / (float)NBATCH;
}

extern "C" void kernel_launch(void* const* d_in, const int* in_sizes, int n_in,
                              void* d_out, int out_size, void* d_ws, size_t ws_size,
                              hipStream_t stream)
{
    const float* y  = (const float*)d_in[0];
    const float* yh = (const float*)d_in[1];
    float* out   = (float*)d_out;
    float* scal  = (float*)d_ws;
    float* cont  = (float*)((char*)d_ws + 4096);
    float* parts = (float*)((char*)d_ws + 8192);

    const size_t per_wg = (size_t)PSTR * sizeof(float);   // 29.4 KB
    int nwg;
    if      (ws_size >= 8192 + 256 * per_wg) nwg = 256;
    else if (ws_size >= 8192 + 128 * per_wg) nwg = 128;
    else                                     nwg = 64;

    yolo_main<<<nwg, THREADS, 0, stream>>>(y, yh, scal, parts, nwg);
    yolo_reduce<<<25, 512, 0, stream>>>(parts, cont, nwg);
    yolo_final<<<1, 256, 0, stream>>>(cont, scal, out, nwg);
}

// Round 24
// 27.806 us; speedup vs baseline: 1.2596x; 1.2596x over previous
//
#include <hip/hip_runtime.h>
#include <math.h>

#define CC 30
#define NBATCH 4096
#define NIJ 49
#define NPAIR 1225            // 49 ij * 25 tail channels (c = 5..29)
#define PSTR 7352             // per-wg partial stride in floats (6*NPAIR=7350, padded /4)
#define F4TOT (PSTR / 4)
#define THREADS 512
#define UF  2940              // floats per 2-batch unit of one tensor
#define UF4 735               // float4 per 2-batch unit of one tensor

// ws layout (NO initialization required — every read location is written first):
//   offset 0      : scal[nwg][4]        (written by yolo_main, 8 KB max)
//   offset 8192   : parts2[8][PSTR]     (written by yolo_reduce)
//   offset 243456 : parts[nwg][PSTR]    (written by yolo_main)

__global__ __launch_bounds__(THREADS)
void yolo_main(const float* __restrict__ y, const float* __restrict__ yh,
               float* __restrict__ scal, float* __restrict__ parts, int nwg)
{
    __shared__ __align__(16) float tY[2][UF];   // 2 x 11.76 KB
    __shared__ __align__(16) float tH[2][UF];   // 2 x 11.76 KB  (total 47 KB -> 2 blocks/CU)
    __shared__ float scr[4][8];

    const int tid = threadIdx.x;
    const int wg  = blockIdx.x;
    const int bpw = NBATCH / nwg;        // 8 for nwg=512
    const int nunit = bpw >> 1;          // 4 two-batch units

    const int i0 = tid;
    const int i1r = tid + 512;
    const int i1  = (i1r < UF4) ? i1r : (UF4 - 1);
    const bool w1 = (i1r < UF4);

    int  ijv[3], cv[3], pr[3];
    bool val[3];
    #pragma unroll
    for (int i = 0; i < 3; i++) {
        int p = tid + i * THREADS;
        val[i] = (p < NPAIR);
        pr[i]  = p;
        int pp = val[i] ? p : 0;
        ijv[i] = pp / 25;
        cv[i]  = 5 + pp % 25;
    }

    float D0[3] = {0,0,0}, B0[3] = {0,0,0}, C0[3] = {0,0,0};
    float D1[3] = {0,0,0}, B1[3] = {0,0,0}, C1[3] = {0,0,0};
    float obj = 0.f, noobj = 0.f, coord = 0.f, tt = 0.f;

    const float4* Yg = (const float4*)y;
    const float4* Hg = (const float4*)yh;

    // prologue: stage unit 0 into buffer 0
    {
        const size_t f4 = (size_t)(wg * nunit) * UF4;
        float4 a0 = Yg[f4+i0], a1 = Yg[f4+i1];
        float4 b0 = Hg[f4+i0], b1 = Hg[f4+i1];
        float4* dY = (float4*)tY[0];
        float4* dH = (float4*)tH[0];
        dY[i0] = a0; if (w1) dY[i1] = a1;
        dH[i0] = b0; if (w1) dH[i1] = b1;
    }
    __syncthreads();

    for (int u = 0; u < nunit; u++) {
        const float* cy = tY[u & 1];
        const float* ch = tH[u & 1];
        const bool pf = (u + 1 < nunit);
        float4 ry0, ry1, rh0, rh1;
        if (pf) {                 // issue next unit's loads; they fly during compute
            const size_t nf4 = (size_t)(wg * nunit + u + 1) * UF4;
            ry0 = Yg[nf4+i0]; ry1 = Yg[nf4+i1];
            rh0 = Hg[nf4+i0]; rh1 = Hg[nf4+i1];
        }

        // ---- pointwise: 98 cells in this unit ----
        if (tid < 2 * NIJ) {
            const int base = tid * CC;
            float y0 = cy[base],     h0 = ch[base];
            float y5 = cy[base + 5], h5 = ch[base + 5];
            float d0 = y0 - h0; d0 *= d0;
            float d5 = y5 - h5; d5 *= d5;
            const bool m0 = (y0 == 1.0f), m1 = (y5 == 1.0f);
            obj   += (m0 ? d0 : 0.f) + (m1 ? d5 : 0.f);
            noobj += (m0 ? 0.f : d0) + (m1 ? 0.f : d5);
            if (m0) {
                float a  = cy[base + 1] - ch[base + 1];
                float b2 = cy[base + 2] - ch[base + 2];
                float c1 = sqrtf(cy[base + 3]) - sqrtf(ch[base + 3]);
                float c2 = sqrtf(cy[base + 4]) - sqrtf(ch[base + 4]);
                coord += a * a + b2 * b2 + c1 * c1 + c2 * c2;
            }
            if (m1) {
                float a  = cy[base + 6] - ch[base + 6];
                float b2 = cy[base + 7] - ch[base + 7];
                float c1 = sqrtf(cy[base + 8]) - sqrtf(ch[base + 8]);
                float c2 = sqrtf(cy[base + 9]) - sqrtf(ch[base + 9]);
                coord += a * a + b2 * b2 + c1 * c1 + c2 * c2;
            }
        }

        // ---- slot phase: 2 batches x 3 slots, register accumulation ----
        #pragma unroll
        for (int b = 0; b < 2; b++) {
            #pragma unroll
            for (int i = 0; i < 3; i++) {
                if (!val[i]) continue;
                const int cb = b * 1470 + ijv[i] * CC;
                const float w0 = (cy[cb] == 1.0f) ? 1.f : 0.f;
                const float wk = (cv[i] >= 10 && cy[cb + 5] == 1.0f) ? 1.f : 0.f;
                const float t  = cy[cb + cv[i]];
                const float th = ch[cb + cv[i]];
                const float e  = __expf(th);
                const float te = t * e, ee = e * e, t2 = t * t;
                D0[i] = fmaf(e,  w0, D0[i]);
                B0[i] = fmaf(te, w0, B0[i]);
                C0[i] = fmaf(ee, w0, C0[i]);
                D1[i] = fmaf(e,  wk, D1[i]);
                B1[i] = fmaf(te, wk, B1[i]);
                C1[i] = fmaf(ee, wk, C1[i]);
                tt = fmaf(t2, w0 + wk, tt);
            }
        }

        // ---- write prefetched unit into the other buffer; ONE barrier per unit ----
        if (pf) {
            float4* dY = (float4*)tY[(u + 1) & 1];
            float4* dH = (float4*)tH[(u + 1) & 1];
            dY[i0] = ry0; if (w1) dY[i1] = ry1;
            dH[i0] = rh0; if (w1) dH[i1] = rh1;
        }
        __syncthreads();
    }

    // ---- per-wg partials: contiguous block, coalesced stores ----
    float* pp = parts + (size_t)wg * PSTR;
    #pragma unroll
    for (int i = 0; i < 3; i++) {
        if (!val[i]) continue;
        const int p = pr[i];
        pp[p]            = D0[i];
        pp[NPAIR + p]    = B0[i];
        pp[2*NPAIR + p]  = C0[i];
        pp[3*NPAIR + p]  = D1[i];   // zero when cv<10
        pp[4*NPAIR + p]  = B1[i];
        pp[5*NPAIR + p]  = C1[i];
    }

    // ---- scalar sums: shuffle -> LDS -> 4 floats per wg ----
    const int lane = tid & 63, wv = tid >> 6;
    #pragma unroll
    for (int off = 32; off > 0; off >>= 1) {
        obj   += __shfl_down(obj,   off);
        noobj += __shfl_down(noobj, off);
        coord += __shfl_down(coord, off);
        tt    += __shfl_down(tt,    off);
    }
    if (lane == 0) { scr[0][wv] = obj; scr[1][wv] = noobj; scr[2][wv] = coord; scr[3][wv] = tt; }
    __syncthreads();
    if (tid < 4) {
        float sacc = 0.f;
        #pragma unroll
        for (int w = 0; w < THREADS / 64; w++) sacc += scr[tid][w];
        scal[wg * 4 + tid] = sacc;
    }
}

// grid (29, 8) x 512: block (bx, cy) sums 64 float4-columns over 1/8 of the wgs
// (8-way sub-split inside the block), float4 loads, LDS fold, plain store.
__global__ __launch_bounds__(512)
void yolo_reduce(const float* __restrict__ parts, float* __restrict__ parts2, int nwg)
{
    const int lane = threadIdx.x & 63;          // float4 column lane
    const int sub  = threadIdx.x >> 6;          // 0..7
    const int f4i  = blockIdx.x * 64 + lane;
    const int cy   = blockIdx.y;                // 0..7
    const int wpc  = nwg >> 3;                  // wgs per chunk (64 for nwg=512)
    const int wps  = wpc >> 3;                  // wgs per sub-group (8)

    float4 s = make_float4(0.f, 0.f, 0.f, 0.f);
    if (f4i < F4TOT) {
        const float* q = parts + (size_t)(cy * wpc + sub * wps) * PSTR + f4i * 4;
        for (int w = 0; w < wps; ++w) {
            float4 a = *(const float4*)q;
            s.x += a.x; s.y += a.y; s.z += a.z; s.w += a.w;
            q += PSTR;
        }
    }
    __shared__ float4 sred[8][64];
    sred[sub][lane] = s;
    __syncthreads();
    if (threadIdx.x < 64 && f4i < F4TOT) {
        float4 t = sred[0][lane];
        #pragma unroll
        for (int c = 1; c < 8; c++) {
            float4 a = sred[c][lane];
            t.x += a.x; t.y += a.y; t.z += a.z; t.w += a.w;
        }
        *(float4*)(parts2 + (size_t)cy * PSTR + f4i * 4) = t;
    }
}

__global__ __launch_bounds__(1024)
void yolo_final(const float* __restrict__ parts2, const float* __restrict__ scal,
                float* __restrict__ out, int nwg)
{
    float v = 0.f;

    for (int s = threadIdx.x; s < NPAIR; s += 1024) {
        const int cidx = s % 25;
        float D0 = 0, B0 = 0, C0 = 0, D1 = 0, B1 = 0, C1 = 0;
        #pragma unroll
        for (int c = 0; c < 8; c++) {
            const float* t = parts2 + (size_t)c * PSTR;
            D0 += t[s];           B0 += t[NPAIR + s];   C0 += t[2*NPAIR + s];
            D1 += t[3*NPAIR + s]; B1 += t[4*NPAIR + s]; C1 += t[5*NPAIR + s];
        }
        if (D0 > 0.f) v += C0 / (D0 * D0) - 2.f * B0 / D0;
        if (cidx >= 5 && D1 > 0.f) v += C1 / (D1 * D1) - 2.f * B1 / D1;
    }

    const float4* s4 = (const float4*)scal;
    for (int w = threadIdx.x; w < nwg; w += 1024) {
        float4 a = s4[w];
        v += a.x + 0.5f * a.y + 5.0f * a.z + a.w;
    }

    __shared__ float sred[16];
    #pragma unroll
    for (int off = 32; off > 0; off >>= 1) v += __shfl_down(v, off);
    const int lane = threadIdx.x & 63, wv = threadIdx.x >> 6;
    if (lane == 0) sred[wv] = v;
    __syncthreads();
    if (threadIdx.x == 0) {
        float tot = 0.f;
        #pragma unroll
        for (int w = 0; w < 16; w++) tot += sred[w];
        out[0] = tot / (float)NBATCH;
    }
}

extern "C" void kernel_launch(void* const* d_in, const int* in_sizes, int n_in,
                              void* d_out, int out_size, void* d_ws, size_t ws_size,
                              hipStream_t stream)
{
    const float* y  = (const float*)d_in[0];
    const float* yh = (const float*)d_in[1];
    float* out    = (float*)d_out;
    float* scal   = (float*)d_ws;
    float* parts2 = (float*)((char*)d_ws + 8192);
    float* parts  = (float*)((char*)d_ws + 243456);

    const size_t per_wg = (size_t)PSTR * sizeof(float);   // 29.4 KB
    int nwg;
    if      (ws_size >= 243456 + 512 * per_wg) nwg = 512;
    else if (ws_size >= 243456 + 256 * per_wg) nwg = 256;
    else                                       nwg = 128;

    yolo_main<<<nwg, THREADS, 0, stream>>>(y, yh, scal, parts, nwg);
    dim3 g2((F4TOT + 63) / 64, 8);
    yolo_reduce<<<g2, 512, 0, stream>>>(parts, parts2, nwg);
    yolo_final<<<1, 1024, 0, stream>>>(parts2, scal, out, nwg);
}

// Round 25
// 27.511 us; speedup vs baseline: 1.2731x; 1.0107x over previous
//
#include <hip/hip_runtime.h>
#include <math.h>

#define CC 30
#define NBATCH 4096
#define NIJ 49
#define NPAIR 1225            // 49 ij * 25 tail channels (c = 5..29)
#define PSTR 7352             // per-wg partial stride in floats (6*NPAIR=7350, padded to /4)
#define F4TOT (PSTR / 4)
#define THREADS 512
#define SLABF4 1470           // float4 count of a 4-batch slab of one tensor
#define SLABF  5880           // floats per 4-batch slab

// ws layout (NO initialization required — every read location is written first):
//   offset 0      : scal[nwg][4]        (written by yolo_main)
//   offset 8192   : parts2[8][PSTR]     (written by yolo_reduce)
//   offset 243456 : parts[nwg][PSTR]    (written by yolo_main)

__global__ __launch_bounds__(THREADS)
void yolo_main(const float* __restrict__ y, const float* __restrict__ yh,
               float* __restrict__ scal, float* __restrict__ parts, int nwg)
{
    __shared__ __align__(16) float tY[2][SLABF];   // 2 x 23.5 KB
    __shared__ __align__(16) float tH[2][SLABF];   // 2 x 23.5 KB
    __shared__ float scr[4][8];

    const int tid = threadIdx.x;
    const int wg  = blockIdx.x;
    const int bpw = NBATCH / nwg;        // 16 for nwg=256
    const int nslab = bpw >> 2;          // 4

    const int i0 = tid, i1 = tid + 512;
    const int i2r = tid + 1024;
    const int i2  = (i2r < SLABF4) ? i2r : (SLABF4 - 1);
    const bool w2 = (i2r < SLABF4);

    int  ijv[3], cv[3], pr[3];
    bool val[3];
    #pragma unroll
    for (int i = 0; i < 3; i++) {
        int p = tid + i * THREADS;
        val[i] = (p < NPAIR);
        pr[i]  = p;
        int pp = val[i] ? p : 0;
        ijv[i] = pp / 25;
        cv[i]  = 5 + pp % 25;
    }

    float D0[3] = {0,0,0}, B0[3] = {0,0,0}, C0[3] = {0,0,0};
    float D1[3] = {0,0,0}, B1[3] = {0,0,0}, C1[3] = {0,0,0};
    float obj = 0.f, noobj = 0.f, coord = 0.f, tt = 0.f;

    const float4* Yg = (const float4*)y;
    const float4* Hg = (const float4*)yh;

    // prologue: stage slab 0 into buffer 0
    {
        const size_t f4 = (size_t)((wg * bpw) >> 2) * SLABF4;
        float4 a0 = Yg[f4+i0], a1 = Yg[f4+i1], a2 = Yg[f4+i2];
        float4 b0 = Hg[f4+i0], b1 = Hg[f4+i1], b2 = Hg[f4+i2];
        float4* dY = (float4*)tY[0];
        float4* dH = (float4*)tH[0];
        dY[i0] = a0; dY[i1] = a1; if (w2) dY[i2] = a2;
        dH[i0] = b0; dH[i1] = b1; if (w2) dH[i2] = b2;
    }
    __syncthreads();

    for (int s = 0; s < nslab; s++) {
        const float* cy = tY[s & 1];
        const float* ch = tH[s & 1];
        const bool pf = (s + 1 < nslab);
        float4 ry0, ry1, ry2, rh0, rh1, rh2;
        if (pf) {                 // issue next slab's loads; they fly during compute
            const size_t nf4 = (size_t)((wg * bpw + (s+1)*4) >> 2) * SLABF4;
            ry0 = Yg[nf4+i0]; ry1 = Yg[nf4+i1]; ry2 = Yg[nf4+i2];
            rh0 = Hg[nf4+i0]; rh1 = Hg[nf4+i1]; rh2 = Hg[nf4+i2];
        }

        // ---- pointwise: 196 cells in this slab ----
        if (tid < 4 * NIJ) {
            const int base = tid * CC;
            float y0 = cy[base],     h0 = ch[base];
            float y5 = cy[base + 5], h5 = ch[base + 5];
            float d0 = y0 - h0; d0 *= d0;
            float d5 = y5 - h5; d5 *= d5;
            const bool m0 = (y0 == 1.0f), m1 = (y5 == 1.0f);
            obj   += (m0 ? d0 : 0.f) + (m1 ? d5 : 0.f);
            noobj += (m0 ? 0.f : d0) + (m1 ? 0.f : d5);
            if (m0) {
                float a  = cy[base + 1] - ch[base + 1];
                float b2 = cy[base + 2] - ch[base + 2];
                float c1 = sqrtf(cy[base + 3]) - sqrtf(ch[base + 3]);
                float c2 = sqrtf(cy[base + 4]) - sqrtf(ch[base + 4]);
                coord += a * a + b2 * b2 + c1 * c1 + c2 * c2;
            }
            if (m1) {
                float a  = cy[base + 6] - ch[base + 6];
                float b2 = cy[base + 7] - ch[base + 7];
                float c1 = sqrtf(cy[base + 8]) - sqrtf(ch[base + 8]);
                float c2 = sqrtf(cy[base + 9]) - sqrtf(ch[base + 9]);
                coord += a * a + b2 * b2 + c1 * c1 + c2 * c2;
            }
        }

        // ---- slot phase: register accumulation, no atomics ----
        #pragma unroll
        for (int b = 0; b < 4; b++) {
            #pragma unroll
            for (int i = 0; i < 3; i++) {
                if (!val[i]) continue;
                const int cb = b * 1470 + ijv[i] * CC;
                const float w0 = (cy[cb] == 1.0f) ? 1.f : 0.f;
                const float wk = (cv[i] >= 10 && cy[cb + 5] == 1.0f) ? 1.f : 0.f;
                const float t  = cy[cb + cv[i]];
                const float th = ch[cb + cv[i]];
                const float e  = __expf(th);
                const float te = t * e, ee = e * e, t2 = t * t;
                D0[i] = fmaf(e,  w0, D0[i]);
                B0[i] = fmaf(te, w0, B0[i]);
                C0[i] = fmaf(ee, w0, C0[i]);
                D1[i] = fmaf(e,  wk, D1[i]);
                B1[i] = fmaf(te, wk, B1[i]);
                C1[i] = fmaf(ee, wk, C1[i]);
                tt = fmaf(t2, w0 + wk, tt);
            }
        }

        // ---- write prefetched slab into the OTHER buffer (its last reader
        //      finished before the previous barrier) — ONE barrier per slab ----
        if (pf) {
            float4* dY = (float4*)tY[(s + 1) & 1];
            float4* dH = (float4*)tH[(s + 1) & 1];
            dY[i0] = ry0; dY[i1] = ry1; if (w2) dY[i2] = ry2;
            dH[i0] = rh0; dH[i1] = rh1; if (w2) dH[i2] = rh2;
        }
        __syncthreads();
    }

    // ---- per-wg partials: contiguous block, coalesced stores ----
    float* pp = parts + (size_t)wg * PSTR;
    #pragma unroll
    for (int i = 0; i < 3; i++) {
        if (!val[i]) continue;
        const int p = pr[i];
        pp[p]            = D0[i];
        pp[NPAIR + p]    = B0[i];
        pp[2*NPAIR + p]  = C0[i];
        pp[3*NPAIR + p]  = D1[i];   // zero when cv<10
        pp[4*NPAIR + p]  = B1[i];
        pp[5*NPAIR + p]  = C1[i];
    }

    // ---- scalar sums: shuffle -> LDS -> 4 floats per wg ----
    const int lane = tid & 63, wv = tid >> 6;
    #pragma unroll
    for (int off = 32; off > 0; off >>= 1) {
        obj   += __shfl_down(obj,   off);
        noobj += __shfl_down(noobj, off);
        coord += __shfl_down(coord, off);
        tt    += __shfl_down(tt,    off);
    }
    if (lane == 0) { scr[0][wv] = obj; scr[1][wv] = noobj; scr[2][wv] = coord; scr[3][wv] = tt; }
    __syncthreads();
    if (tid < 4) {
        float sacc = 0.f;
        #pragma unroll
        for (int w = 0; w < THREADS / 64; w++) sacc += scr[tid][w];
        scal[wg * 4 + tid] = sacc;
    }
}

// grid (29, 8) x 512: block (bx, cy) sums 64 float4-columns over 1/8 of the wgs
// (8-way sub-split inside the block), float4 loads, LDS fold, plain store.
__global__ __launch_bounds__(512)
void yolo_reduce(const float* __restrict__ parts, float* __restrict__ parts2, int nwg)
{
    const int lane = threadIdx.x & 63;          // float4 column lane
    const int sub  = threadIdx.x >> 6;          // 0..7
    const int f4i  = blockIdx.x * 64 + lane;
    const int cy   = blockIdx.y;                // 0..7
    const int wpc  = nwg >> 3;                  // wgs per chunk (32 for nwg=256)
    const int wps  = wpc >> 3;                  // wgs per sub-group (4)

    float4 s = make_float4(0.f, 0.f, 0.f, 0.f);
    if (f4i < F4TOT) {
        const float* q = parts + (size_t)(cy * wpc + sub * wps) * PSTR + f4i * 4;
        for (int w = 0; w < wps; ++w) {
            float4 a = *(const float4*)q;
            s.x += a.x; s.y += a.y; s.z += a.z; s.w += a.w;
            q += PSTR;
        }
    }
    __shared__ float4 sred[8][64];
    sred[sub][lane] = s;
    __syncthreads();
    if (threadIdx.x < 64 && f4i < F4TOT) {
        float4 t = sred[0][lane];
        #pragma unroll
        for (int c = 1; c < 8; c++) {
            float4 a = sred[c][lane];
            t.x += a.x; t.y += a.y; t.z += a.z; t.w += a.w;
        }
        *(float4*)(parts2 + (size_t)cy * PSTR + f4i * 4) = t;
    }
}

__global__ __launch_bounds__(1024)
void yolo_final(const float* __restrict__ parts2, const float* __restrict__ scal,
                float* __restrict__ out, int nwg)
{
    float v = 0.f;

    for (int s = threadIdx.x; s < NPAIR; s += 1024) {
        const int cidx = s % 25;
        float D0 = 0, B0 = 0, C0 = 0, D1 = 0, B1 = 0, C1 = 0;
        #pragma unroll
        for (int c = 0; c < 8; c++) {
            const float* t = parts2 + (size_t)c * PSTR;
            D0 += t[s];           B0 += t[NPAIR + s];   C0 += t[2*NPAIR + s];
            D1 += t[3*NPAIR + s]; B1 += t[4*NPAIR + s]; C1 += t[5*NPAIR + s];
        }
        if (D0 > 0.f) v += C0 / (D0 * D0) - 2.f * B0 / D0;
        if (cidx >= 5 && D1 > 0.f) v += C1 / (D1 * D1) - 2.f * B1 / D1;
    }

    const float4* s4 = (const float4*)scal;
    for (int w = threadIdx.x; w < nwg; w += 1024) {
        float4 a = s4[w];
        v += a.x + 0.5f * a.y + 5.0f * a.z + a.w;
    }

    __shared__ float sred[16];
    #pragma unroll
    for (int off = 32; off > 0; off >>= 1) v += __shfl_down(v, off);
    const int lane = threadIdx.x & 63, wv = threadIdx.x >> 6;
    if (lane == 0) sred[wv] = v;
    __syncthreads();
    if (threadIdx.x == 0) {
        float tot = 0.f;
        #pragma unroll
        for (int w = 0; w < 16; w++) tot += sred[w];
        out[0] = tot / (float)NBATCH;
    }
}

extern "C" void kernel_launch(void* const* d_in, const int* in_sizes, int n_in,
                              void* d_out, int out_size, void* d_ws, size_t ws_size,
                              hipStream_t stream)
{
    const float* y  = (const float*)d_in[0];
    const float* yh = (const float*)d_in[1];
    float* out    = (float*)d_out;
    float* scal   = (float*)d_ws;
    float* parts2 = (float*)((char*)d_ws + 8192);
    float* parts  = (float*)((char*)d_ws + 243456);

    const size_t per_wg = (size_t)PSTR * sizeof(float);   // 29.4 KB
    int nwg;
    if      (ws_size >= 243456 + 256 * per_wg) nwg = 256;
    else if (ws_size >= 243456 + 128 * per_wg) nwg = 128;
    else                                       nwg = 64;

    yolo_main<<<nwg, THREADS, 0, stream>>>(y, yh, scal, parts, nwg);
    dim3 g2((F4TOT + 63) / 64, 8);
    yolo_reduce<<<g2, 512, 0, stream>>>(parts, parts2, nwg);
    yolo_final<<<1, 1024, 0, stream>>>(parts2, scal, out, nwg);
}